// Round 1
// baseline (2319.710 us; speedup 1.0000x reference)
//
#include <hip/hip_runtime.h>

// ---------------------------------------------------------------------------
// SchNet-style GNN on MI355X.
// N=50000 atoms, E=1600000 edges, H=128, F=64, G=50, L=3, NG=256.
// Edge filter MLP via bf16 MFMA 16x16x32 (fragment-order LDS tiles).
// Node GEMMs via per-lane fp32 dot products with uniform (s_load) weights.
// ---------------------------------------------------------------------------

typedef short bf16x8 __attribute__((ext_vector_type(8)));
typedef float floatx4 __attribute__((ext_vector_type(4)));

#define HCH 128
#define FCH 64
#define GCH 50
#define LN  3

__device__ __forceinline__ unsigned short f2bf(float x) {
    unsigned int u = __float_as_uint(x);
    unsigned int r = (u + 0x7FFFu + ((u >> 16) & 1u)) >> 16;
    return (unsigned short)r;
}

__device__ __forceinline__ float sspf(float x) {
    // softplus(x) - log(2), numerically stable
    float ax = fabsf(x);
    return fmaxf(x, 0.f) + __logf(1.f + __expf(-ax)) - 0.69314718056f;
}

// ---------------------------------------------------------------------------
// Prep: permute edge-MLP weights into MFMA B-fragment order (bf16), transpose
// node weights so per-node dot products read contiguous (uniform) rows.
// ---------------------------------------------------------------------------
__global__ void k_prep(const float* __restrict__ mw1, const float* __restrict__ mw2,
                       const float* __restrict__ l1w, const float* __restrict__ l2w,
                       const float* __restrict__ lw,  const float* __restrict__ ow1,
                       short* __restrict__ mw1p, short* __restrict__ mw2p,
                       float* __restrict__ l1wT, float* __restrict__ l2wT,
                       float* __restrict__ lwT,  float* __restrict__ ow1T)
{
    int tid = blockIdx.x * blockDim.x + threadIdx.x;
    int nthr = gridDim.x * blockDim.x;

    // B-fragment order: idx = ((nt*2+kk)*64 + lane)*8 + j
    // element: k = kk*32 + (lane>>4)*8 + j ; f = nt*16 + (lane&15)
    for (int i = tid; i < LN * 4096; i += nthr) {
        int l = i >> 12; int idx = i & 4095;
        int j  = idx & 7;
        int ln = (idx >> 3) & 63;
        int kk = (idx >> 9) & 1;
        int nt = (idx >> 10) & 3;
        int k = kk * 32 + (ln >> 4) * 8 + j;
        int f = nt * 16 + (ln & 15);
        float v1 = (k < GCH) ? mw1[(l * GCH + k) * FCH + f] : 0.f;
        mw1p[i] = (short)f2bf(v1);
        mw2p[i] = (short)f2bf(mw2[(l * 64 + k) * 64 + f]);
    }
    for (int i = tid; i < LN * FCH * HCH; i += nthr) {      // l1wT[l][f][k]
        int l = i / (FCH * HCH); int rem = i % (FCH * HCH);
        int f = rem >> 7; int k = rem & 127;
        l1wT[i] = l1w[l * HCH * FCH + k * FCH + f];
    }
    for (int i = tid; i < LN * HCH * FCH; i += nthr) {      // l2wT[l][o][k]
        int l = i / (HCH * FCH); int rem = i % (HCH * FCH);
        int o = rem >> 6; int k = rem & 63;
        l2wT[i] = l2w[l * FCH * HCH + k * HCH + o];
    }
    for (int i = tid; i < LN * HCH * HCH; i += nthr) {      // lwT[l][o][k]
        int l = i / (HCH * HCH); int rem = i % (HCH * HCH);
        int o = rem >> 7; int k = rem & 127;
        lwT[i] = lw[l * HCH * HCH + k * HCH + o];
    }
    for (int i = tid; i < (HCH / 2) * HCH; i += nthr) {     // ow1T[f][k]
        int f = i >> 7; int k = i & 127;
        ow1T[i] = ow1[k * (HCH / 2) + f];
    }
}

// ---------------------------------------------------------------------------
// Edge geometry: d and cosine cutoff per edge (computed once, reused 3 layers)
// ---------------------------------------------------------------------------
__global__ void k_geom(const int* __restrict__ ei, const float* __restrict__ pos,
                       float* __restrict__ dE, float* __restrict__ CE, int E)
{
    int e = blockIdx.x * blockDim.x + threadIdx.x;
    if (e >= E) return;
    int s = ei[e], t = ei[E + e];
    float dx = pos[s * 3 + 0] - pos[t * 3 + 0];
    float dy = pos[s * 3 + 1] - pos[t * 3 + 1];
    float dz = pos[s * 3 + 2] - pos[t * 3 + 2];
    float d = sqrtf(dx * dx + dy * dy + dz * dz);
    dE[e] = d;
    CE[e] = 0.5f * (__cosf(d * 0.31415926535897932f) + 1.f);
}

// ---------------------------------------------------------------------------
// Embedding gather: h[n][k] = emb[z[n]][k]
// ---------------------------------------------------------------------------
__global__ void k_embed(const int* __restrict__ z, const float* __restrict__ emb,
                        float* __restrict__ h, int N)
{
    int tid = blockIdx.x * blockDim.x + threadIdx.x;
    if (tid < N * HCH) {
        int n = tid >> 7; int k = tid & 127;
        h[tid] = emb[z[n] * HCH + k];
    }
}

// ---------------------------------------------------------------------------
// xj = h @ l1w[layer]  ([N,128]@[128,64]); per-lane node, uniform weights
// ---------------------------------------------------------------------------
__global__ __launch_bounds__(64) void k_l1(const float* __restrict__ h,
                                           const float* __restrict__ l1wT,
                                           float* __restrict__ xj, int layer, int N)
{
    int n = blockIdx.x * 64 + threadIdx.x;
    bool act = (n < N);
    int nn = act ? n : (N - 1);
    float x[HCH];
    const float4* hr = (const float4*)(h + (size_t)nn * HCH);
#pragma unroll
    for (int i = 0; i < HCH / 4; i++) {
        float4 v = hr[i];
        x[4 * i] = v.x; x[4 * i + 1] = v.y; x[4 * i + 2] = v.z; x[4 * i + 3] = v.w;
    }
    const float* W = l1wT + layer * FCH * HCH;
    for (int f = 0; f < FCH; f++) {
        const float* wr = W + f * HCH;
        float a0 = 0.f, a1 = 0.f, a2 = 0.f, a3 = 0.f;
#pragma unroll
        for (int k = 0; k < HCH; k += 4) {
            a0 += x[k] * wr[k];
            a1 += x[k + 1] * wr[k + 1];
            a2 += x[k + 2] * wr[k + 2];
            a3 += x[k + 3] * wr[k + 3];
        }
        if (act) xj[(size_t)nn * FCH + f] = (a0 + a1) + (a2 + a3);
    }
}

// ---------------------------------------------------------------------------
// Edge filter MLP + message + scatter. 64 edges/block, 4 waves, bf16 MFMA.
// Wave w owns edge rows 16w..16w+15 (M-tile); 4 N-tiles of 16; K=64 (2 steps).
// ---------------------------------------------------------------------------
__global__ __launch_bounds__(256) void k_edge(
    const float* __restrict__ dE, const float* __restrict__ CE,
    const int* __restrict__ ei, const float* __restrict__ xj,
    const short* __restrict__ mw1p, const short* __restrict__ mw2p,
    const float* __restrict__ mb1, const float* __restrict__ mb2,
    float* __restrict__ agg, int layer, int E, int N)
{
    __shared__ __align__(16) short A1[4096];   // ea tile, A-fragment order
    __shared__ __align__(16) short A2[4096];   // ssp(t1) tile, A-fragment order
    __shared__ __align__(16) short B1[4096];   // mw1 frag order
    __shared__ __align__(16) short B2[4096];   // mw2 frag order
    __shared__ float dL[64], cL[64];
    __shared__ int   sL[64], tL[64];
    __shared__ float b1L[64], b2L[64];

    int t = threadIdx.x;
    int e0 = blockIdx.x * 64;

    // stage fragment-ordered weights: 8KB each = 512 uint4
    {
        const uint4* w1 = (const uint4*)(mw1p + layer * 4096);
        const uint4* w2 = (const uint4*)(mw2p + layer * 4096);
        ((uint4*)B1)[t] = w1[t];
        ((uint4*)B1)[t + 256] = w1[t + 256];
        ((uint4*)B2)[t] = w2[t];
        ((uint4*)B2)[t + 256] = w2[t + 256];
    }
    if (t < 64) {
        int eg = e0 + t;
        if (eg < E) {
            dL[t] = dE[eg]; cL[t] = CE[eg];
            sL[t] = ei[eg]; tL[t] = ei[E + eg];
        } else {
            dL[t] = 0.f; cL[t] = 0.f; sL[t] = 0; tL[t] = 0;
        }
        b1L[t] = mb1[layer * 64 + t];
        b2L[t] = mb2[layer * 64 + t];
    }
    __syncthreads();

    // Gaussian smearing -> A1 in A-fragment order.
    // off(r,k): w=r>>4, kk=k>>5, q=(k>>3)&3, j=k&7, l2=(r&15)+16q
    // short index = w*1024 + kk*512 + l2*8 + j
    const float step = 10.f / 49.f;
    const float coeff = -0.5f / (step * step);
    for (int i2 = t; i2 < 2048; i2 += 256) {
        int r = i2 >> 5;
        int k0 = (i2 & 31) * 2;
        float dr = dL[r];
        float ea = 0.f, eb = 0.f;
        if (k0 < GCH)     { float u = dr - k0 * step;      ea = __expf(coeff * u * u); }
        if (k0 + 1 < GCH) { float u = dr - (k0 + 1) * step; eb = __expf(coeff * u * u); }
        unsigned int pk = (unsigned int)f2bf(ea) | ((unsigned int)f2bf(eb) << 16);
        int w  = r >> 4;
        int kk = k0 >> 5;
        int q  = (k0 >> 3) & 3;
        int j  = k0 & 7;
        int l2 = (r & 15) + 16 * q;
        int si = w * 1024 + kk * 512 + l2 * 8 + j;
        *(unsigned int*)(&A1[si]) = pk;
    }
    __syncthreads();

    int lane = t & 63;
    int w = t >> 6;
    int quad = lane >> 4;
    int col = lane & 15;

    floatx4 acc[4];

    // GEMM1: t1 = ea @ mw1 + mb1
    {
        bf16x8 a0 = *(const bf16x8*)(&A1[w * 1024 + lane * 8]);
        bf16x8 a1 = *(const bf16x8*)(&A1[w * 1024 + 512 + lane * 8]);
#pragma unroll
        for (int nt = 0; nt < 4; nt++) {
            float bias = b1L[nt * 16 + col];
            floatx4 c = {bias, bias, bias, bias};
            bf16x8 b0 = *(const bf16x8*)(&B1[(nt * 2 + 0) * 512 + lane * 8]);
            bf16x8 b1 = *(const bf16x8*)(&B1[(nt * 2 + 1) * 512 + lane * 8]);
            c = __builtin_amdgcn_mfma_f32_16x16x32_bf16(a0, b0, c, 0, 0, 0);
            c = __builtin_amdgcn_mfma_f32_16x16x32_bf16(a1, b1, c, 0, 0, 0);
            acc[nt] = c;
        }
    }

    // ssp, write to A2 in A-fragment order (C/D layout: row=quad*4+reg, col)
#pragma unroll
    for (int nt = 0; nt < 4; nt++) {
        int f = nt * 16 + col;
        int kk2 = f >> 5;
        int q2 = (f >> 3) & 3;
        int j2 = f & 7;
#pragma unroll
        for (int reg = 0; reg < 4; reg++) {
            int rloc = quad * 4 + reg;
            float v = sspf(acc[nt][reg]);
            int si = w * 1024 + kk2 * 512 + (rloc + 16 * q2) * 8 + j2;
            A2[si] = (short)f2bf(v);
        }
    }
    __syncthreads();

    // GEMM2: W = t1 @ mw2 + mb2
    {
        bf16x8 a0 = *(const bf16x8*)(&A2[w * 1024 + lane * 8]);
        bf16x8 a1 = *(const bf16x8*)(&A2[w * 1024 + 512 + lane * 8]);
#pragma unroll
        for (int nt = 0; nt < 4; nt++) {
            float bias = b2L[nt * 16 + col];
            floatx4 c = {bias, bias, bias, bias};
            bf16x8 b0 = *(const bf16x8*)(&B2[(nt * 2 + 0) * 512 + lane * 8]);
            bf16x8 b1 = *(const bf16x8*)(&B2[(nt * 2 + 1) * 512 + lane * 8]);
            c = __builtin_amdgcn_mfma_f32_16x16x32_bf16(a0, b0, c, 0, 0, 0);
            c = __builtin_amdgcn_mfma_f32_16x16x32_bf16(a1, b1, c, 0, 0, 0);
            acc[nt] = c;
        }
    }

    // epilogue: msg = W * C * xj[src], scatter-add into agg[dst]
#pragma unroll
    for (int nt = 0; nt < 4; nt++) {
        int f = nt * 16 + col;
#pragma unroll
        for (int reg = 0; reg < 4; reg++) {
            int r = w * 16 + quad * 4 + reg;
            if (e0 + r < E) {
                float wv = acc[nt][reg] * cL[r];
                int s = sL[r];
                int dd = tL[r];
                float m = wv * xj[(size_t)s * FCH + f];
                unsafeAtomicAdd(&agg[(size_t)dd * FCH + f], m);
            }
        }
    }
}

// ---------------------------------------------------------------------------
// Node update: x = ssp(agg@l2w + l2b) @ lw + lb ; h += x
// ---------------------------------------------------------------------------
__global__ __launch_bounds__(64) void k_update(const float* __restrict__ agg,
    const float* __restrict__ l2wT, const float* __restrict__ l2b,
    const float* __restrict__ lwT,  const float* __restrict__ lb,
    float* __restrict__ h, int layer, int N)
{
    __shared__ float yl[64 * 132];
    int lane = threadIdx.x;
    int n = blockIdx.x * 64 + lane;
    bool act = (n < N);
    int nn = act ? n : (N - 1);

    float a[FCH];
    const float4* ar = (const float4*)(agg + (size_t)nn * FCH);
#pragma unroll
    for (int i = 0; i < FCH / 4; i++) {
        float4 v = ar[i];
        a[4 * i] = v.x; a[4 * i + 1] = v.y; a[4 * i + 2] = v.z; a[4 * i + 3] = v.w;
    }

    const float* W2 = l2wT + layer * HCH * FCH;
    const float* B2 = l2b + layer * HCH;
    for (int f = 0; f < HCH; f++) {
        const float* wr = W2 + f * FCH;
        float a0 = 0.f, a1 = 0.f, a2 = 0.f, a3 = 0.f;
#pragma unroll
        for (int k = 0; k < FCH; k += 4) {
            a0 += a[k] * wr[k];
            a1 += a[k + 1] * wr[k + 1];
            a2 += a[k + 2] * wr[k + 2];
            a3 += a[k + 3] * wr[k + 3];
        }
        yl[lane * 132 + f] = sspf((a0 + a1) + (a2 + a3) + B2[f]);
    }

    float y[HCH];
#pragma unroll
    for (int i = 0; i < HCH / 4; i++) {
        float4 v = *(const float4*)(&yl[lane * 132 + 4 * i]);
        y[4 * i] = v.x; y[4 * i + 1] = v.y; y[4 * i + 2] = v.z; y[4 * i + 3] = v.w;
    }

    const float* W3 = lwT + layer * HCH * HCH;
    const float* B3 = lb + layer * HCH;
    for (int o = 0; o < HCH; o++) {
        const float* wr = W3 + o * HCH;
        float a0 = 0.f, a1 = 0.f, a2 = 0.f, a3 = 0.f;
#pragma unroll
        for (int k = 0; k < HCH; k += 4) {
            a0 += y[k] * wr[k];
            a1 += y[k + 1] * wr[k + 1];
            a2 += y[k + 2] * wr[k + 2];
            a3 += y[k + 3] * wr[k + 3];
        }
        if (act) h[(size_t)nn * HCH + o] += (a0 + a1) + (a2 + a3) + B3[o];
    }
}

// ---------------------------------------------------------------------------
// Readout: out[g] += ssp(h@ow1+ob1)@ow2 + ob2 per atom
// ---------------------------------------------------------------------------
__global__ __launch_bounds__(64) void k_readout(const float* __restrict__ h,
    const float* __restrict__ ow1T, const float* __restrict__ ob1,
    const float* __restrict__ ow2,  const float* __restrict__ ob2,
    const int* __restrict__ batch, float* __restrict__ out, int N)
{
    int n = blockIdx.x * 64 + threadIdx.x;
    if (n >= N) return;
    float x[HCH];
    const float4* hr = (const float4*)(h + (size_t)n * HCH);
#pragma unroll
    for (int i = 0; i < HCH / 4; i++) {
        float4 v = hr[i];
        x[4 * i] = v.x; x[4 * i + 1] = v.y; x[4 * i + 2] = v.z; x[4 * i + 3] = v.w;
    }
    float val = ob2[0];
    for (int f = 0; f < HCH / 2; f++) {
        const float* wr = ow1T + f * HCH;
        float a0 = 0.f, a1 = 0.f, a2 = 0.f, a3 = 0.f;
#pragma unroll
        for (int k = 0; k < HCH; k += 4) {
            a0 += x[k] * wr[k];
            a1 += x[k + 1] * wr[k + 1];
            a2 += x[k + 2] * wr[k + 2];
            a3 += x[k + 3] * wr[k + 3];
        }
        val += sspf((a0 + a1) + (a2 + a3) + ob1[f]) * ow2[f];
    }
    unsafeAtomicAdd(&out[batch[n]], val);
}

// ---------------------------------------------------------------------------
extern "C" void kernel_launch(void* const* d_in, const int* in_sizes, int n_in,
                              void* d_out, int out_size, void* d_ws, size_t ws_size,
                              hipStream_t stream)
{
    const int*   z    = (const int*)d_in[0];
    const float* pos  = (const float*)d_in[1];
    const int*   batc = (const int*)d_in[2];
    const int*   ei   = (const int*)d_in[3];
    const float* emb  = (const float*)d_in[4];
    const float* mw1  = (const float*)d_in[5];
    const float* mb1  = (const float*)d_in[6];
    const float* mw2  = (const float*)d_in[7];
    const float* mb2  = (const float*)d_in[8];
    const float* l1w  = (const float*)d_in[9];
    const float* l2w  = (const float*)d_in[10];
    const float* l2b  = (const float*)d_in[11];
    const float* lw   = (const float*)d_in[12];
    const float* lb   = (const float*)d_in[13];
    const float* ow1  = (const float*)d_in[14];
    const float* ob1  = (const float*)d_in[15];
    const float* ow2  = (const float*)d_in[16];
    const float* ob2  = (const float*)d_in[17];
    float* out = (float*)d_out;

    int N = in_sizes[0];
    int E = in_sizes[3] / 2;

    char* ws = (char*)d_ws;
    size_t off = 0;
    float* h    = (float*)(ws + off); off += (size_t)N * HCH * 4;
    float* xj   = (float*)(ws + off); off += (size_t)N * FCH * 4;
    float* agg  = (float*)(ws + off); off += (size_t)N * FCH * 4;
    float* dE   = (float*)(ws + off); off += (size_t)E * 4;
    float* CE   = (float*)(ws + off); off += (size_t)E * 4;
    short* mw1p = (short*)(ws + off); off += LN * 4096 * 2;
    short* mw2p = (short*)(ws + off); off += LN * 4096 * 2;
    float* l1wT = (float*)(ws + off); off += LN * FCH * HCH * 4;
    float* l2wT = (float*)(ws + off); off += LN * HCH * FCH * 4;
    float* lwT  = (float*)(ws + off); off += LN * HCH * HCH * 4;
    float* ow1T = (float*)(ws + off); off += (HCH / 2) * HCH * 4;

    k_prep<<<64, 256, 0, stream>>>(mw1, mw2, l1w, l2w, lw, ow1,
                                   mw1p, mw2p, l1wT, l2wT, lwT, ow1T);
    k_geom<<<(E + 255) / 256, 256, 0, stream>>>(ei, pos, dE, CE, E);
    k_embed<<<(N * HCH + 255) / 256, 256, 0, stream>>>(z, emb, h, N);
    hipMemsetAsync(out, 0, (size_t)out_size * sizeof(float), stream);

    int NB = (N + 63) / 64;
    int EB = (E + 63) / 64;
    for (int l = 0; l < LN; l++) {
        k_l1<<<NB, 64, 0, stream>>>(h, l1wT, xj, l, N);
        hipMemsetAsync(agg, 0, (size_t)N * FCH * 4, stream);
        k_edge<<<EB, 256, 0, stream>>>(dE, CE, ei, xj, mw1p, mw2p, mb1, mb2,
                                       agg, l, E, N);
        k_update<<<NB, 64, 0, stream>>>(agg, l2wT, l2b, lwT, lb, h, l, N);
    }
    k_readout<<<NB, 64, 0, stream>>>(h, ow1T, ob1, ow2, ob2, batc, out, N);
}

// Round 2
// 993.239 us; speedup vs baseline: 2.3355x; 2.3355x over previous
//
#include <hip/hip_runtime.h>

// ---------------------------------------------------------------------------
// SchNet-style GNN on MI355X — R2.
// N=50000, E=1600000, H=128, F=64, G=50, L=3, NG=256.
// - Edges counting-sorted by dst each call; edge kernel does wave-local
//   segmented reduction in LDS -> ~8x fewer device atomics.
// - All node GEMMs on bf16 MFMA 16x16x32, fused per layer, barrier-free
//   (per-wave-private LDS A-fragment regions).
// ---------------------------------------------------------------------------

typedef short bf16x8 __attribute__((ext_vector_type(8)));
typedef float floatx4 __attribute__((ext_vector_type(4)));

#define HCH 128
#define FCH 64
#define GCH 50
#define LN  3

#define MFMA(a, b, c) __builtin_amdgcn_mfma_f32_16x16x32_bf16((a), (b), (c), 0, 0, 0)

__device__ __forceinline__ unsigned short f2bf(float x) {
    unsigned int u = __float_as_uint(x);
    unsigned int r = (u + 0x7FFFu + ((u >> 16) & 1u)) >> 16;
    return (unsigned short)r;
}

__device__ __forceinline__ float sspf(float x) {
    float ax = fabsf(x);
    return fmaxf(x, 0.f) + __logf(1.f + __expf(-ax)) - 0.69314718056f;
}

// ---------------------------------------------------------------------------
// B-fragment fill: src row-major [Ksrc x F] (zero-padded to K), dst frag order
// i = ((nt*(K/32)+kk)*64 + lane)*8 + j ; element k=kk*32+(lane>>4)*8+j,
// f=nt*16+(lane&15).
// ---------------------------------------------------------------------------
__device__ __forceinline__ void fill_frag(const float* __restrict__ src,
                                          short* __restrict__ dst,
                                          int K, int F, int Ksrc,
                                          int tid, int nthr)
{
    int kc = K >> 5;
    int total = (F >> 4) * kc * 512;
    for (int i = tid; i < total; i += nthr) {
        int j = i & 7;
        int lane = (i >> 3) & 63;
        int rest = i >> 9;
        int kk = rest % kc;
        int nt = rest / kc;
        int k = kk * 32 + ((lane >> 4) << 3) + j;
        int f = nt * 16 + (lane & 15);
        float v = (k < Ksrc) ? src[k * F + f] : 0.f;
        dst[i] = (short)f2bf(v);
    }
}

__global__ void k_prep(const float* __restrict__ mw1, const float* __restrict__ mw2,
                       const float* __restrict__ l1w, const float* __restrict__ l2w,
                       const float* __restrict__ lw,  const float* __restrict__ ow1,
                       short* __restrict__ mw1p, short* __restrict__ mw2p,
                       short* __restrict__ l1wp, short* __restrict__ l2wp,
                       short* __restrict__ lwp,  short* __restrict__ ow1p)
{
    int tid = blockIdx.x * blockDim.x + threadIdx.x;
    int nthr = gridDim.x * blockDim.x;
    for (int l = 0; l < LN; l++) {
        fill_frag(mw1 + l * GCH * FCH, mw1p + l * 4096, 64, 64, GCH, tid, nthr);
        fill_frag(mw2 + l * FCH * FCH, mw2p + l * 4096, 64, 64, 64, tid, nthr);
        fill_frag(l1w + l * HCH * FCH, l1wp + l * 8192, 128, 64, 128, tid, nthr);
        fill_frag(l2w + l * FCH * HCH, l2wp + l * 8192, 64, 128, 64, tid, nthr);
        fill_frag(lw  + l * HCH * HCH, lwp  + l * 16384, 128, 128, 128, tid, nthr);
    }
    fill_frag(ow1, ow1p, 128, 64, 128, tid, nthr);
}

// ---------------------------------------------------------------------------
// Counting sort of edges by dst: hist -> scan -> scatter
// ---------------------------------------------------------------------------
__global__ void k_hist(const int* __restrict__ ei, int* __restrict__ hist, int E)
{
    int e = blockIdx.x * blockDim.x + threadIdx.x;
    if (e < E) atomicAdd(&hist[ei[E + e]], 1);
}

__global__ __launch_bounds__(1024) void k_scan(const int* __restrict__ hist,
                                               int* __restrict__ cursor, int N)
{
    __shared__ int part[1024];
    int t = threadIdx.x;
    int b = t * 49;
    int s = 0;
    for (int i = 0; i < 49; i++) { int idx = b + i; if (idx < N) s += hist[idx]; }
    part[t] = s;
    __syncthreads();
    for (int off = 1; off < 1024; off <<= 1) {
        int v = (t >= off) ? part[t - off] : 0;
        __syncthreads();
        part[t] += v;
        __syncthreads();
    }
    int run = (t > 0) ? part[t - 1] : 0;
    for (int i = 0; i < 49; i++) {
        int idx = b + i;
        if (idx < N) { cursor[idx] = run; run += hist[idx]; }
    }
}

__global__ void k_scatter(const int* __restrict__ ei, int* __restrict__ cursor,
                          int* __restrict__ sS, int* __restrict__ sD, int E)
{
    int e = blockIdx.x * blockDim.x + threadIdx.x;
    if (e < E) {
        int d = ei[E + e];
        int p = atomicAdd(&cursor[d], 1);
        sS[p] = ei[e];
        sD[p] = d;
    }
}

// ---------------------------------------------------------------------------
// Geometry on sorted edges
// ---------------------------------------------------------------------------
__global__ void k_geom(const int* __restrict__ sS, const int* __restrict__ sD,
                       const float* __restrict__ pos,
                       float* __restrict__ dE, float* __restrict__ CE, int E)
{
    int e = blockIdx.x * blockDim.x + threadIdx.x;
    if (e >= E) return;
    int s = sS[e], t = sD[e];
    float dx = pos[s * 3 + 0] - pos[t * 3 + 0];
    float dy = pos[s * 3 + 1] - pos[t * 3 + 1];
    float dz = pos[s * 3 + 2] - pos[t * 3 + 2];
    float d = sqrtf(dx * dx + dy * dy + dz * dz);
    dE[e] = d;
    CE[e] = 0.5f * (__cosf(d * 0.31415926535897932f) + 1.f);
}

// ---------------------------------------------------------------------------
// k_node0: h = emb[z]; xj = h @ l1w[0]
// ---------------------------------------------------------------------------
__global__ __launch_bounds__(256) void k_node0(const int* __restrict__ z,
    const float* __restrict__ emb, const short* __restrict__ l1wp0,
    float* __restrict__ h, float* __restrict__ xj, int N)
{
    __shared__ __align__(16) short A3[8192];
    __shared__ int zL[64];
    int t = threadIdx.x, lane = t & 63, w = t >> 6;
    int n0 = blockIdx.x * 64;
    if (t < 64) { int n = n0 + t; zL[t] = (n < N) ? z[n] : 0; }
    __syncthreads();
#pragma unroll
    for (int m = 0; m < 16; m++) {
        int ii = lane + 64 * m;          // 16 rows x 64 k-pairs
        int rloc = ii >> 6;
        int k0 = (ii & 63) * 2;
        int n = n0 + w * 16 + rloc;
        float2 v = make_float2(0.f, 0.f);
        if (n < N) {
            v = *(const float2*)(&emb[(size_t)zL[w * 16 + rloc] * HCH + k0]);
            *(float2*)(&h[(size_t)n * HCH + k0]) = v;
        }
        unsigned pk = (unsigned)f2bf(v.x) | ((unsigned)f2bf(v.y) << 16);
        int si = w * 2048 + (k0 >> 5) * 512 + (rloc + 16 * ((k0 >> 3) & 3)) * 8 + (k0 & 7);
        *(unsigned*)(&A3[si]) = pk;
    }
    int quad = lane >> 4, col = lane & 15;
    const bf16x8* B = (const bf16x8*)l1wp0;
    bf16x8 af[4];
#pragma unroll
    for (int kk = 0; kk < 4; kk++)
        af[kk] = *(const bf16x8*)(&A3[w * 2048 + kk * 512 + lane * 8]);
#pragma unroll
    for (int nt = 0; nt < 4; nt++) {
        floatx4 c = {0.f, 0.f, 0.f, 0.f};
#pragma unroll
        for (int kk = 0; kk < 4; kk++) c = MFMA(af[kk], B[(nt * 4 + kk) * 64 + lane], c);
        int f = nt * 16 + col;
#pragma unroll
        for (int reg = 0; reg < 4; reg++) {
            int n = n0 + w * 16 + quad * 4 + reg;
            if (n < N) xj[(size_t)n * FCH + f] = c[reg];
        }
    }
}

// ---------------------------------------------------------------------------
// Edge kernel: filter MLP (MFMA) + message + segmented reduce + atomics.
// Edges sorted by dst. 64 edges/block, 4 waves, per-wave-private LDS.
// ---------------------------------------------------------------------------
__global__ __launch_bounds__(256) void k_edge(
    const float* __restrict__ dE, const float* __restrict__ CE,
    const int* __restrict__ sS, const int* __restrict__ sD,
    const float* __restrict__ xj,
    const short* __restrict__ mw1p, const short* __restrict__ mw2p,
    const float* __restrict__ mb1, const float* __restrict__ mb2,
    float* __restrict__ agg, int layer, int E)
{
    __shared__ __align__(16) short A1[4096];
    __shared__ __align__(16) short A2[4096];
    __shared__ __align__(16) float M[64 * 68];
    __shared__ float dL[64], cL[64];
    __shared__ int sL[64], tL[64];

    int t = threadIdx.x;
    int e0 = blockIdx.x * 64;
    if (t < 64) {
        int eg = e0 + t;
        if (eg < E) { dL[t] = dE[eg]; cL[t] = CE[eg]; sL[t] = sS[eg]; tL[t] = sD[eg]; }
        else        { dL[t] = 0.f;   cL[t] = 0.f;    sL[t] = 0;      tL[t] = -1; }
    }
    __syncthreads();   // only barrier in this kernel

    int lane = t & 63, w = t >> 6;
    // Gaussian smearing into this wave's A1 region (A-fragment order, K=64)
    const float step = 10.f / 49.f;
    const float coeff = -0.5f / (step * step);
#pragma unroll
    for (int m = 0; m < 8; m++) {
        int ii = lane + 64 * m;           // 16 rows x 32 k-pairs
        int rloc = ii >> 5;
        int k0 = (ii & 31) * 2;
        float dr = dL[w * 16 + rloc];
        float ea = 0.f, eb = 0.f;
        if (k0 < GCH)     { float u = dr - k0 * step;       ea = __expf(coeff * u * u); }
        if (k0 + 1 < GCH) { float u = dr - (k0 + 1) * step; eb = __expf(coeff * u * u); }
        unsigned pk = (unsigned)f2bf(ea) | ((unsigned)f2bf(eb) << 16);
        int si = w * 1024 + (k0 >> 5) * 512 + (rloc + 16 * ((k0 >> 3) & 3)) * 8 + (k0 & 7);
        *(unsigned*)(&A1[si]) = pk;
    }
    int quad = lane >> 4, col = lane & 15;
    const bf16x8* B1 = (const bf16x8*)(mw1p + layer * 4096);
    const bf16x8* B2 = (const bf16x8*)(mw2p + layer * 4096);
    floatx4 acc[4];

    bf16x8 a0 = *(const bf16x8*)(&A1[w * 1024 + lane * 8]);
    bf16x8 a1 = *(const bf16x8*)(&A1[w * 1024 + 512 + lane * 8]);
#pragma unroll
    for (int nt = 0; nt < 4; nt++) {
        float bias = mb1[layer * FCH + nt * 16 + col];
        floatx4 c = {bias, bias, bias, bias};
        c = MFMA(a0, B1[(nt * 2 + 0) * 64 + lane], c);
        c = MFMA(a1, B1[(nt * 2 + 1) * 64 + lane], c);
        acc[nt] = c;
    }
    // ssp -> A2 (A-fragment order), same-wave region
#pragma unroll
    for (int nt = 0; nt < 4; nt++) {
        int f = nt * 16 + col;
        int si0 = w * 1024 + (f >> 5) * 512 + (16 * ((f >> 3) & 3)) * 8 + (f & 7);
#pragma unroll
        for (int reg = 0; reg < 4; reg++)
            A2[si0 + (quad * 4 + reg) * 8] = (short)f2bf(sspf(acc[nt][reg]));
    }
    bf16x8 a2 = *(const bf16x8*)(&A2[w * 1024 + lane * 8]);
    bf16x8 a3 = *(const bf16x8*)(&A2[w * 1024 + 512 + lane * 8]);
#pragma unroll
    for (int nt = 0; nt < 4; nt++) {
        float bias = mb2[layer * FCH + nt * 16 + col];
        floatx4 c = {bias, bias, bias, bias};
        c = MFMA(a2, B2[(nt * 2 + 0) * 64 + lane], c);
        c = MFMA(a3, B2[(nt * 2 + 1) * 64 + lane], c);
        acc[nt] = c;
    }
    // msg = W * C * xj[src]  -> LDS M (stride 68 kills write conflicts)
#pragma unroll
    for (int nt = 0; nt < 4; nt++) {
        int f = nt * 16 + col;
#pragma unroll
        for (int reg = 0; reg < 4; reg++) {
            int r = w * 16 + quad * 4 + reg;
            float mv = acc[nt][reg] * cL[r] * xj[(size_t)sL[r] * FCH + f];
            M[r * 68 + f] = mv;
        }
    }
    // segmented reduce over this wave's 16 sorted rows; one thread per f
    {
        int f = lane;
        int base = w * 16;
        float a = 0.f;
        int cur = tL[base];
#pragma unroll
        for (int i = 0; i < 16; i++) {
            int r = base + i;
            int d = tL[r];
            if (d != cur) {
                if (cur >= 0) unsafeAtomicAdd(&agg[(size_t)cur * FCH + f], a);
                a = 0.f; cur = d;
            }
            a += M[r * 68 + f];
        }
        if (cur >= 0) unsafeAtomicAdd(&agg[(size_t)cur * FCH + f], a);
    }
}

// ---------------------------------------------------------------------------
// Node update (layers 0,1): x=ssp(agg@l2w+b); x=x@lw+b; h+=x; xj=h@l1w[l+1]
// 64 nodes/block, 4 waves, barrier-free (per-wave LDS regions).
// ---------------------------------------------------------------------------
__global__ __launch_bounds__(256) void k_update(
    const float* __restrict__ agg, const short* __restrict__ l2wp,
    const float* __restrict__ l2b, const short* __restrict__ lwp,
    const float* __restrict__ lb,  const short* __restrict__ l1wp_next,
    float* __restrict__ h, float* __restrict__ xj, int layer, int N)
{
    __shared__ __align__(16) short Aa[4096];
    __shared__ __align__(16) short A2[8192];
    __shared__ __align__(16) short A3[8192];
    int t = threadIdx.x, lane = t & 63, w = t >> 6;
    int n0 = blockIdx.x * 64;
#pragma unroll
    for (int m = 0; m < 8; m++) {
        int ii = lane + 64 * m;          // 16 rows x 32 k-pairs (K=64)
        int rloc = ii >> 5;
        int k0 = (ii & 31) * 2;
        int n = n0 + w * 16 + rloc;
        float2 v = make_float2(0.f, 0.f);
        if (n < N) v = *(const float2*)(&agg[(size_t)n * FCH + k0]);
        unsigned pk = (unsigned)f2bf(v.x) | ((unsigned)f2bf(v.y) << 16);
        int si = w * 1024 + (k0 >> 5) * 512 + (rloc + 16 * ((k0 >> 3) & 3)) * 8 + (k0 & 7);
        *(unsigned*)(&Aa[si]) = pk;
    }
    int quad = lane >> 4, col = lane & 15;
    const bf16x8* Bl2 = (const bf16x8*)(l2wp + layer * 8192);
    const bf16x8* Blw = (const bf16x8*)(lwp + layer * 16384);
    const bf16x8* Bl1 = (const bf16x8*)l1wp_next;

    bf16x8 a0 = *(const bf16x8*)(&Aa[w * 1024 + lane * 8]);
    bf16x8 a1 = *(const bf16x8*)(&Aa[w * 1024 + 512 + lane * 8]);
    // GEMM1: [64x64]@[64x128] + l2b, ssp -> A2
#pragma unroll
    for (int nt = 0; nt < 8; nt++) {
        float bias = l2b[layer * HCH + nt * 16 + col];
        floatx4 c = {bias, bias, bias, bias};
        c = MFMA(a0, Bl2[(nt * 2 + 0) * 64 + lane], c);
        c = MFMA(a1, Bl2[(nt * 2 + 1) * 64 + lane], c);
        int f = nt * 16 + col;
        int si0 = w * 2048 + (f >> 5) * 512 + (16 * ((f >> 3) & 3)) * 8 + (f & 7);
#pragma unroll
        for (int reg = 0; reg < 4; reg++)
            A2[si0 + (quad * 4 + reg) * 8] = (short)f2bf(sspf(c[reg]));
    }
    bf16x8 af[4];
#pragma unroll
    for (int kk = 0; kk < 4; kk++)
        af[kk] = *(const bf16x8*)(&A2[w * 2048 + kk * 512 + lane * 8]);
    // GEMM2: [64x128]@[128x128] + lb ; residual ; -> h, A3
#pragma unroll
    for (int nt = 0; nt < 8; nt++) {
        float bias = lb[layer * HCH + nt * 16 + col];
        floatx4 c = {bias, bias, bias, bias};
#pragma unroll
        for (int kk = 0; kk < 4; kk++) c = MFMA(af[kk], Blw[(nt * 4 + kk) * 64 + lane], c);
        int f = nt * 16 + col;
        int si0 = w * 2048 + (f >> 5) * 512 + (16 * ((f >> 3) & 3)) * 8 + (f & 7);
#pragma unroll
        for (int reg = 0; reg < 4; reg++) {
            int n = n0 + w * 16 + quad * 4 + reg;
            float hv = 0.f;
            if (n < N) {
                hv = h[(size_t)n * HCH + f] + c[reg];
                h[(size_t)n * HCH + f] = hv;
            }
            A3[si0 + (quad * 4 + reg) * 8] = (short)f2bf(hv);
        }
    }
    // GEMM3: xj = h_new @ l1w[layer+1]
#pragma unroll
    for (int kk = 0; kk < 4; kk++)
        af[kk] = *(const bf16x8*)(&A3[w * 2048 + kk * 512 + lane * 8]);
#pragma unroll
    for (int nt = 0; nt < 4; nt++) {
        floatx4 c = {0.f, 0.f, 0.f, 0.f};
#pragma unroll
        for (int kk = 0; kk < 4; kk++) c = MFMA(af[kk], Bl1[(nt * 4 + kk) * 64 + lane], c);
        int f = nt * 16 + col;
#pragma unroll
        for (int reg = 0; reg < 4; reg++) {
            int n = n0 + w * 16 + quad * 4 + reg;
            if (n < N) xj[(size_t)n * FCH + f] = c[reg];
        }
    }
}

// ---------------------------------------------------------------------------
// Final layer: node update (no xj) + output MLP + per-graph atomic readout
// ---------------------------------------------------------------------------
__global__ __launch_bounds__(256) void k_final(
    const float* __restrict__ agg, const short* __restrict__ l2wp,
    const float* __restrict__ l2b, const short* __restrict__ lwp,
    const float* __restrict__ lb,  const short* __restrict__ ow1p,
    const float* __restrict__ ob1, const float* __restrict__ ow2,
    const float* __restrict__ ob2, const int* __restrict__ batch,
    const float* __restrict__ h, float* __restrict__ out, int layer, int N)
{
    __shared__ __align__(16) short Aa[4096];
    __shared__ __align__(16) short A2[8192];
    __shared__ __align__(16) short A3[8192];
    __shared__ float R[64 * 17];
    int t = threadIdx.x, lane = t & 63, w = t >> 6;
    int n0 = blockIdx.x * 64;
#pragma unroll
    for (int m = 0; m < 8; m++) {
        int ii = lane + 64 * m;
        int rloc = ii >> 5;
        int k0 = (ii & 31) * 2;
        int n = n0 + w * 16 + rloc;
        float2 v = make_float2(0.f, 0.f);
        if (n < N) v = *(const float2*)(&agg[(size_t)n * FCH + k0]);
        unsigned pk = (unsigned)f2bf(v.x) | ((unsigned)f2bf(v.y) << 16);
        int si = w * 1024 + (k0 >> 5) * 512 + (rloc + 16 * ((k0 >> 3) & 3)) * 8 + (k0 & 7);
        *(unsigned*)(&Aa[si]) = pk;
    }
    int quad = lane >> 4, col = lane & 15;
    const bf16x8* Bl2 = (const bf16x8*)(l2wp + layer * 8192);
    const bf16x8* Blw = (const bf16x8*)(lwp + layer * 16384);
    const bf16x8* Bow = (const bf16x8*)ow1p;

    bf16x8 a0 = *(const bf16x8*)(&Aa[w * 1024 + lane * 8]);
    bf16x8 a1 = *(const bf16x8*)(&Aa[w * 1024 + 512 + lane * 8]);
#pragma unroll
    for (int nt = 0; nt < 8; nt++) {
        float bias = l2b[layer * HCH + nt * 16 + col];
        floatx4 c = {bias, bias, bias, bias};
        c = MFMA(a0, Bl2[(nt * 2 + 0) * 64 + lane], c);
        c = MFMA(a1, Bl2[(nt * 2 + 1) * 64 + lane], c);
        int f = nt * 16 + col;
        int si0 = w * 2048 + (f >> 5) * 512 + (16 * ((f >> 3) & 3)) * 8 + (f & 7);
#pragma unroll
        for (int reg = 0; reg < 4; reg++)
            A2[si0 + (quad * 4 + reg) * 8] = (short)f2bf(sspf(c[reg]));
    }
    bf16x8 af[4];
#pragma unroll
    for (int kk = 0; kk < 4; kk++)
        af[kk] = *(const bf16x8*)(&A2[w * 2048 + kk * 512 + lane * 8]);
#pragma unroll
    for (int nt = 0; nt < 8; nt++) {
        float bias = lb[layer * HCH + nt * 16 + col];
        floatx4 c = {bias, bias, bias, bias};
#pragma unroll
        for (int kk = 0; kk < 4; kk++) c = MFMA(af[kk], Blw[(nt * 4 + kk) * 64 + lane], c);
        int f = nt * 16 + col;
        int si0 = w * 2048 + (f >> 5) * 512 + (16 * ((f >> 3) & 3)) * 8 + (f & 7);
#pragma unroll
        for (int reg = 0; reg < 4; reg++) {
            int n = n0 + w * 16 + quad * 4 + reg;
            float hv = 0.f;
            if (n < N) hv = h[(size_t)n * HCH + f] + c[reg];
            A3[si0 + (quad * 4 + reg) * 8] = (short)f2bf(hv);
        }
    }
#pragma unroll
    for (int kk = 0; kk < 4; kk++)
        af[kk] = *(const bf16x8*)(&A3[w * 2048 + kk * 512 + lane * 8]);
    float p[4] = {0.f, 0.f, 0.f, 0.f};
#pragma unroll
    for (int nt = 0; nt < 4; nt++) {
        float bias = ob1[nt * 16 + col];
        floatx4 c = {bias, bias, bias, bias};
#pragma unroll
        for (int kk = 0; kk < 4; kk++) c = MFMA(af[kk], Bow[(nt * 4 + kk) * 64 + lane], c);
        float w2 = ow2[nt * 16 + col];
#pragma unroll
        for (int reg = 0; reg < 4; reg++) p[reg] += sspf(c[reg]) * w2;
    }
#pragma unroll
    for (int reg = 0; reg < 4; reg++)
        R[(w * 16 + quad * 4 + reg) * 17 + col] = p[reg];
    __syncthreads();
    if (t < 64) {
        int n = n0 + t;
        if (n < N) {
            float v = ob2[0];
#pragma unroll
            for (int c2 = 0; c2 < 16; c2++) v += R[t * 17 + c2];
            unsafeAtomicAdd(&out[batch[n]], v);
        }
    }
}

// ---------------------------------------------------------------------------
extern "C" void kernel_launch(void* const* d_in, const int* in_sizes, int n_in,
                              void* d_out, int out_size, void* d_ws, size_t ws_size,
                              hipStream_t stream)
{
    const int*   z    = (const int*)d_in[0];
    const float* pos  = (const float*)d_in[1];
    const int*   batc = (const int*)d_in[2];
    const int*   ei   = (const int*)d_in[3];
    const float* emb  = (const float*)d_in[4];
    const float* mw1  = (const float*)d_in[5];
    const float* mb1  = (const float*)d_in[6];
    const float* mw2  = (const float*)d_in[7];
    const float* mb2  = (const float*)d_in[8];
    const float* l1w  = (const float*)d_in[9];
    const float* l2w  = (const float*)d_in[10];
    const float* l2b  = (const float*)d_in[11];
    const float* lw   = (const float*)d_in[12];
    const float* lb   = (const float*)d_in[13];
    const float* ow1  = (const float*)d_in[14];
    const float* ob1  = (const float*)d_in[15];
    const float* ow2  = (const float*)d_in[16];
    const float* ob2  = (const float*)d_in[17];
    float* out = (float*)d_out;

    int N = in_sizes[0];
    int E = in_sizes[3] / 2;

    char* ws = (char*)d_ws;
    size_t off = 0;
    auto alloc = [&](size_t bytes) {
        void* p = ws + off;
        off = (off + bytes + 255) & ~(size_t)255;
        return p;
    };
    float* h      = (float*)alloc((size_t)N * HCH * 4);
    float* xj     = (float*)alloc((size_t)N * FCH * 4);
    float* agg    = (float*)alloc((size_t)N * FCH * 4);
    float* dE     = (float*)alloc((size_t)E * 4);
    float* CE     = (float*)alloc((size_t)E * 4);
    int*   sS     = (int*)alloc((size_t)E * 4);
    int*   sD     = (int*)alloc((size_t)E * 4);
    int*   hist   = (int*)alloc((size_t)N * 4);
    int*   cursor = (int*)alloc((size_t)N * 4);
    short* mw1p   = (short*)alloc(LN * 4096 * 2);
    short* mw2p   = (short*)alloc(LN * 4096 * 2);
    short* l1wp   = (short*)alloc(LN * 8192 * 2);
    short* l2wp   = (short*)alloc(LN * 8192 * 2);
    short* lwp    = (short*)alloc(LN * 16384 * 2);
    short* ow1p   = (short*)alloc(8192 * 2);

    int EB256 = (E + 255) / 256;
    int NB = (N + 63) / 64;
    int EB = (E + 63) / 64;

    k_prep<<<64, 256, 0, stream>>>(mw1, mw2, l1w, l2w, lw, ow1,
                                   mw1p, mw2p, l1wp, l2wp, lwp, ow1p);
    hipMemsetAsync(hist, 0, (size_t)N * 4, stream);
    k_hist<<<EB256, 256, 0, stream>>>(ei, hist, E);
    k_scan<<<1, 1024, 0, stream>>>(hist, cursor, N);
    k_scatter<<<EB256, 256, 0, stream>>>(ei, cursor, sS, sD, E);
    k_geom<<<EB256, 256, 0, stream>>>(sS, sD, pos, dE, CE, E);
    hipMemsetAsync(out, 0, (size_t)out_size * sizeof(float), stream);

    k_node0<<<NB, 256, 0, stream>>>(z, emb, l1wp, h, xj, N);
    for (int l = 0; l < LN; l++) {
        hipMemsetAsync(agg, 0, (size_t)N * FCH * 4, stream);
        k_edge<<<EB, 256, 0, stream>>>(dE, CE, sS, sD, xj, mw1p, mw2p,
                                       mb1, mb2, agg, l, E);
        if (l < LN - 1) {
            k_update<<<NB, 256, 0, stream>>>(agg, l2wp, l2b, lwp, lb,
                                             l1wp + (l + 1) * 8192, h, xj, l, N);
        } else {
            k_final<<<NB, 256, 0, stream>>>(agg, l2wp, l2b, lwp, lb, ow1p,
                                            ob1, ow2, ob2, batc, h, out, l, N);
        }
    }
}